// Round 4
// baseline (3763.284 us; speedup 1.0000x reference)
//
#include <hip/hip_runtime.h>

// LSTM stack, B=256 rows (one block each), T=1024 steps.
// Round 4: SPLIT=8 lanes per unit (k-slices) so per-thread weights
// (96/96/80/48 floats) fit the arch-VGPR budget -> no v_accvgpr_read
// round-trips (round 3's hidden 2x VALU tax). Dot products use packed
// v_pk_fma_f32 via float2 + __builtin_elementwise_fma (fp32 peak needs
// packed). 8-lane reduction done with DPP (quad_perm xor1/xor2 +
// row_half_mirror) -> pure VALU, no ds_bpermute. Double-buffered [x;h]
// in LDS, ONE barrier per step.

#define BATCH 256
#define TSTEPS 1024

typedef float v2f __attribute__((ext_vector_type(2)));

__device__ __forceinline__ v2f fma2(v2f a, v2f b, v2f c) {
#if __has_builtin(__builtin_elementwise_fma)
    return __builtin_elementwise_fma(a, b, c);
#else
    v2f r; r.x = fmaf(a.x, b.x, c.x); r.y = fmaf(a.y, b.y, c.y); return r;
#endif
}

template<int CTRL>
__device__ __forceinline__ float red_step(float v) {
    int t = __builtin_amdgcn_update_dpp(0, __float_as_int(v), CTRL, 0xF, 0xF, true);
    return v + __int_as_float(t);
}

// sum across the 8 lanes of an (aligned) 8-lane group, result in all lanes
__device__ __forceinline__ float red8(float v) {
    v = red_step<0xB1>(v);   // quad_perm(1,0,3,2): xor 1
    v = red_step<0x4E>(v);   // quad_perm(2,3,0,1): xor 2
    v = red_step<0x141>(v);  // row_half_mirror: partner in other quad of the 8-group
    return v;
}

__device__ __forceinline__ float sigm(float x) {
    return 1.0f / (1.0f + __expf(-x));
}

__device__ __forceinline__ float tanh_fast(float x) {
    float ax = fabsf(x);
    float e = __expf(2.0f * ax);
    float r = 1.0f - 2.0f / (e + 1.0f);
    return copysignf(r, x);
}

// SPLIT is fixed at 8 (divides 64: groups never straddle a wave).
// S: per-lane slice length (mult of 4, 8*S >= DIN+U). BLOCK >= 8*U.
template<int DIN, int U, int S, int BLOCK, bool LAST>
__global__ __launch_bounds__(BLOCK, 1)
void lstm_layer(const float* __restrict__ xin,   // [B, T, DIN]
                const float* __restrict__ Wx,    // [DIN, 4U]
                const float* __restrict__ Wh,    // [U, 4U]
                const float* __restrict__ bias,  // [4U]
                float* __restrict__ xout,        // [B, T, U] (unless LAST)
                const float* __restrict__ Wout,  // [U] (LAST only)
                const float* __restrict__ bout,  // [1] (LAST only)
                float* __restrict__ dout)        // [B] (LAST only)
{
    constexpr int G  = 4 * U;
    constexpr int K  = DIN + U;
    constexpr int KP = 8 * S;
    static_assert(KP >= K, "slice coverage");
    static_assert((S % 4) == 0, "float4 alignment");

    const int b   = blockIdx.x;
    const int tid = threadIdx.x;
    const int u   = tid >> 3;            // unit owned by this 8-lane group
    const int s   = tid & 7;             // k-slice within the group
    const bool active = (u < U);
    const int uu  = active ? u : 0;

    __shared__ __align__(16) float s_xh[2][KP];

    // zero both buffers: h0 = 0, pad region [K..KP) must stay 0 forever
    for (int i = tid; i < 2 * KP; i += BLOCK) ((float*)s_xh)[i] = 0.0f;

    // ---- this lane's k-slice of its unit's 4 gate columns, as float2 ----
    v2f w2[4][S / 2];
    float bj[4];
#pragma unroll
    for (int g = 0; g < 4; ++g) {
        const int col = g * U + uu;
        bj[g] = bias[col];
#pragma unroll
        for (int j = 0; j < S / 2; ++j) {
            v2f v;
#pragma unroll
            for (int e = 0; e < 2; ++e) {
                const int k = s * S + 2 * j + e;
                float x = 0.0f;
                if (k < DIN)    x = Wx[k * G + col];
                else if (k < K) x = Wh[(k - DIN) * G + col];
                v[e] = x;
            }
            w2[g][j] = v;
        }
    }

    const float* xrow = xin + (size_t)b * TSTEPS * DIN;
    if (tid < DIN) s_xh[0][tid] = xrow[tid];   // x_0
    __syncthreads();

    float c = 0.0f;
    int cur = 0;

    for (int t = 0; t < TSTEPS; ++t, cur ^= 1) {
        // prefetch x_{t+1}; latency hides under the FMA phase
        float xn = 0.0f;
        if (t + 1 < TSTEPS && tid < DIN) xn = xrow[(size_t)(t + 1) * DIN + tid];

        // ---- packed partial dots over this lane's k-slice (4 gates) ----
        v2f a0 = {0.0f, 0.0f}, a1 = a0, a2 = a0, a3 = a0;
        const float* xh = &s_xh[cur][s * S];
#pragma unroll
        for (int kk = 0; kk < S; kk += 4) {
            float4 v = *(const float4*)(xh + kk);   // ds_read_b128, broadcast x8
            v2f lo = {v.x, v.y};
            v2f hi = {v.z, v.w};
            const int j = kk >> 1;
            a0 = fma2(lo, w2[0][j], a0);
            a0 = fma2(hi, w2[0][j + 1], a0);
            a1 = fma2(lo, w2[1][j], a1);
            a1 = fma2(hi, w2[1][j + 1], a1);
            a2 = fma2(lo, w2[2][j], a2);
            a2 = fma2(hi, w2[2][j + 1], a2);
            a3 = fma2(lo, w2[3][j], a3);
            a3 = fma2(hi, w2[3][j + 1], a3);
        }

        // ---- DPP butterfly across the 8 lanes (pure VALU) ----
        float g0 = red8(a0.x + a0.y);
        float g1 = red8(a1.x + a1.y);
        float g2 = red8(a2.x + a2.y);
        float g3 = red8(a3.x + a3.y);

        const int nxt = cur ^ 1;
        if (active && s == 0) {
            const float fi = sigm(g0 + bj[0]);
            const float ff = sigm(g1 + bj[1]);
            const float tc = tanh_fast(g2 + bj[2]);
            const float fo = sigm(g3 + bj[3]);
            c = ff * c + fi * tc;
            const float h = fo * tanh_fast(c);
            s_xh[nxt][DIN + u] = h;
            if (!LAST) xout[((size_t)b * TSTEPS + t) * U + u] = h;
        }
        if (tid < DIN) s_xh[nxt][tid] = xn;
        __syncthreads();   // nxt buffer complete; cur buffer free for reuse
    }

    if (LAST && tid == 0) {
        // after the loop, cur indexes the buffer holding h_T
        float acc = bout[0];
#pragma unroll
        for (int k = 0; k < U; ++k) acc = fmaf(s_xh[cur][DIN + k], Wout[k], acc);
        dout[b] = acc;
    }
}

extern "C" void kernel_launch(void* const* d_in, const int* in_sizes, int n_in,
                              void* d_out, int out_size, void* d_ws, size_t ws_size,
                              hipStream_t stream)
{
    const float* seq  = (const float*)d_in[0];
    const float* Wx0  = (const float*)d_in[1];
    const float* Wh0  = (const float*)d_in[2];
    const float* b0   = (const float*)d_in[3];
    const float* Wx1  = (const float*)d_in[4];
    const float* Wh1  = (const float*)d_in[5];
    const float* b1   = (const float*)d_in[6];
    const float* Wx2  = (const float*)d_in[7];
    const float* Wh2  = (const float*)d_in[8];
    const float* b2   = (const float*)d_in[9];
    const float* Wx3  = (const float*)d_in[10];
    const float* Wh3  = (const float*)d_in[11];
    const float* b3   = (const float*)d_in[12];
    const float* Wout = (const float*)d_in[13];
    const float* bout = (const float*)d_in[14];
    float* out = (float*)d_out;

    float* ws = (float*)d_ws;
    float* X1 = ws;                                   // [256,1024,100]
    float* X2 = ws + (size_t)BATCH * TSTEPS * 100;    // [256,1024,80]
    float* X3 = ws;                                   // [256,1024,50] reuses X1

    dim3 grid(BATCH);

    // K = DIN+U:        164        180        130        80
    // wts/thread(f32):   96         96         80        48   (all fit arch VGPRs)
    lstm_layer<64, 100, 24, 832, false><<<grid, 832, 0, stream>>>(
        seq, Wx0, Wh0, b0, X1, nullptr, nullptr, nullptr);
    lstm_layer<100, 80, 24, 640, false><<<grid, 640, 0, stream>>>(
        X1, Wx1, Wh1, b1, X2, nullptr, nullptr, nullptr);
    lstm_layer<80, 50, 20, 448, false><<<grid, 448, 0, stream>>>(
        X2, Wx2, Wh2, b2, X3, nullptr, nullptr, nullptr);
    lstm_layer<50, 30, 12, 256, true><<<grid, 256, 0, stream>>>(
        X3, Wx3, Wh3, b3, nullptr, Wout, bout, out);
}

// Round 5
// 3369.585 us; speedup vs baseline: 1.1168x; 1.1168x over previous
//
#include <hip/hip_runtime.h>

// Round 5: two-phase LSTM stack.
// Phase A (xg_gemm): xg = x @ Wx + b  — parallel tiled fp32 GEMM (64x64 tile,
//   K <= 100 staged whole in LDS; A staged transposed in 4-k-chunks, rows
//   assigned ty+16r so broadcast b128 reads are bank-conflict-free).
// Phase B (lstm_rec): recurrence, dot only over h (K=U). 4 lanes per unit,
//   weights 32..112 floats/thread (pure arch VGPRs). xg streamed from global
//   with 2-step lookahead into double-buffered LDS. DPP quad butterfly +
//   distributed activations. ONE barrier per step.
// Time processed in 8 chunks of 128 steps (ws budget: 2xXG + 2xXc + state
// = 132 MB < 189 MB known-safe). c/h persist in ws between chunks.

#define BATCH 256
#define TFULL 1024
#define TC    128
#define NCHUNK (TFULL / TC)

__device__ __forceinline__ float sigm(float x) {
    return 1.0f / (1.0f + __expf(-x));
}

__device__ __forceinline__ float tanh_fast(float x) {
    float ax = fabsf(x);
    float e = __expf(2.0f * ax);
    float r = 1.0f - 2.0f / (e + 1.0f);
    return copysignf(r, x);
}

template<int CTRL>
__device__ __forceinline__ float dpp_add(float v) {
    int t = __builtin_amdgcn_update_dpp(0, __float_as_int(v), CTRL, 0xF, 0xF, true);
    return v + __int_as_float(t);
}
template<int CTRL>
__device__ __forceinline__ float dpp_mov(float v) {
    int t = __builtin_amdgcn_update_dpp(0, __float_as_int(v), CTRL, 0xF, 0xF, true);
    return __int_as_float(t);
}

// ---------------- Phase A: xg = x @ Wx + bias ----------------
// x rows addressed as b*batchStride + t*K + k (b = row/128, t = row%128).
// out: [32768, N] chunk-local, row-major. Tile: 64 rows x 64 cols, BLOCK=256,
// thread = 4 rows (ty+16r) x 4 cols (4tx).
template<int K, int N>
__global__ __launch_bounds__(256, 2)
void xg_gemm(const float* __restrict__ x, int batchStride,
             const float* __restrict__ Wx,    // [K, N]
             const float* __restrict__ bias,  // [N]
             float* __restrict__ out)
{
    constexpr int K4   = (K + 3) / 4;
    constexpr int SLAB = 64 * 4 + 4;          // words per k4-slab (+4 pad)

    const int n0   = blockIdx.x * 64;
    const int row0 = blockIdx.y * 64;
    const int tid  = threadIdx.x;
    const int tx   = tid & 15;
    const int ty   = tid >> 4;

    __shared__ __align__(16) float s_A[K4 * SLAB];   // [k4][row][ksub]
    __shared__ __align__(16) float s_B[K4 * 4 * 64]; // [k][col]

    // ---- stage A transposed ----
    if constexpr ((K % 4) == 0) {
        for (int i = tid; i < 64 * (K / 4); i += 256) {
            const int row = i / (K / 4);
            const int k4  = i % (K / 4);
            const int gr  = row0 + row;
            const int b   = gr >> 7;
            const int t   = gr & 127;
            float4 v = *(const float4*)(x + (size_t)b * batchStride + t * K + k4 * 4);
            *(float4*)(s_A + k4 * SLAB + row * 4) = v;
        }
    } else {
        for (int i = tid; i < 64 * K; i += 256) {
            const int row = i / K;
            const int k   = i % K;
            const int gr  = row0 + row;
            const int b   = gr >> 7;
            const int t   = gr & 127;
            s_A[(k >> 2) * SLAB + row * 4 + (k & 3)] =
                x[(size_t)b * batchStride + t * K + k];
        }
        constexpr int PAD = K4 * 4 - K;
        for (int i = tid; i < 64 * PAD; i += 256) {
            const int row = i / PAD;
            const int kk  = K + i % PAD;
            s_A[(kk >> 2) * SLAB + row * 4 + (kk & 3)] = 0.0f;
        }
    }

    // ---- stage B (zero-pad k >= K and cols >= N) ----
    for (int i = tid; i < K4 * 4 * 16; i += 256) {
        const int k  = i >> 4;
        const int c4 = i & 15;
        float4 v = {0.0f, 0.0f, 0.0f, 0.0f};
        if (k < K && n0 + c4 * 4 < N)
            v = *(const float4*)(Wx + (size_t)k * N + n0 + c4 * 4);
        *(float4*)(s_B + k * 64 + c4 * 4) = v;
    }
    __syncthreads();

    float acc[4][4];
#pragma unroll
    for (int r = 0; r < 4; ++r)
#pragma unroll
        for (int c = 0; c < 4; ++c) acc[r][c] = 0.0f;

    for (int k4 = 0; k4 < K4; ++k4) {
        float4 bv[4];
#pragma unroll
        for (int j = 0; j < 4; ++j)
            bv[j] = *(const float4*)(s_B + (k4 * 4 + j) * 64 + tx * 4);
#pragma unroll
        for (int r = 0; r < 4; ++r) {
            float4 av = *(const float4*)(s_A + k4 * SLAB + (ty + 16 * r) * 4);
#pragma unroll
            for (int c = 0; c < 4; ++c) {
                acc[r][c] = fmaf(av.x, ((const float*)&bv[0])[c], acc[r][c]);
                acc[r][c] = fmaf(av.y, ((const float*)&bv[1])[c], acc[r][c]);
                acc[r][c] = fmaf(av.z, ((const float*)&bv[2])[c], acc[r][c]);
                acc[r][c] = fmaf(av.w, ((const float*)&bv[3])[c], acc[r][c]);
            }
        }
    }

    if (n0 + tx * 4 < N) {
        float4 bb = *(const float4*)(bias + n0 + tx * 4);
#pragma unroll
        for (int r = 0; r < 4; ++r) {
            float4 o;
            o.x = acc[r][0] + bb.x;
            o.y = acc[r][1] + bb.y;
            o.z = acc[r][2] + bb.z;
            o.w = acc[r][3] + bb.w;
            *(float4*)(out + (size_t)(row0 + ty + 16 * r) * N + n0 + tx * 4) = o;
        }
    }
}

// ---------------- Phase B: recurrence over one 128-step chunk ----------------
// 4 lanes per unit (quad-aligned). Lane s owns gate s's column slice.
// S: per-lane k-slice (mult of 4, 4*S >= U). BLOCK >= max(4*U, G/4).
template<int U, int S, int BLOCK, bool LAST>
__global__ __launch_bounds__(BLOCK, 1)
void lstm_rec(const float* __restrict__ xg,   // [B, TC, G]
              const float* __restrict__ Wh,   // [U, G]
              float* __restrict__ xout,       // [B, TC, U] (unless LAST)
              float* __restrict__ c_state,    // [B*U]
              float* __restrict__ h_state,    // [B*U]
              int first,
              const float* __restrict__ Wout, // [U] (LAST)
              const float* __restrict__ bout, // [1] (LAST)
              float* __restrict__ dout)       // [B] (LAST)
{
    constexpr int G = 4 * U;

    const int b   = blockIdx.x;
    const int tid = threadIdx.x;
    const int u   = tid >> 2;
    const int s   = tid & 3;
    const bool act_th = (u < U);
    const int uu  = act_th ? u : 0;

    __shared__ __align__(16) float s_h[2][4 * S];
    __shared__ __align__(16) float s_xg[2][G];

    // ---- weights: this lane's k-slice of gate column s*U+u ----
    float w[S];
#pragma unroll
    for (int kk = 0; kk < S; ++kk) {
        const int k = s * S + kk;  // NOTE: slice of the SAME gate per lane? No:
        w[kk] = 0.0f;              // (overwritten below)
    }
    // Each lane accumulates partials for ALL 4 gates over its k-slice.
    float w4[4][S];
#pragma unroll
    for (int g = 0; g < 4; ++g)
#pragma unroll
        for (int kk = 0; kk < S; ++kk) {
            const int k = s * S + kk;
            w4[g][kk] = (act_th && k < U) ? Wh[(size_t)k * G + g * U + uu] : 0.0f;
        }

    // zero both h buffers (pads must stay 0)
    for (int i = tid; i < 2 * 4 * S; i += BLOCK) ((float*)s_h)[i] = 0.0f;
    __syncthreads();
    if (tid < U) s_h[0][tid] = first ? 0.0f : h_state[b * U + tid];

    float c = first ? 0.0f : c_state[b * U + uu];   // replicated across the quad
    if (first) c = 0.0f;

    const float* xgrow = xg + (size_t)b * TC * G;
    float4 xgn = {0.0f, 0.0f, 0.0f, 0.0f};
    if (tid < G / 4) {
        ((float4*)s_xg[0])[tid] = ((const float4*)xgrow)[tid];
        xgn = ((const float4*)(xgrow + G))[tid];
    }
    __syncthreads();

    int cur = 0;
    float h = 0.0f;
    const bool is_t = (s == 2);

    for (int t = 0; t < TC; ++t, cur ^= 1) {
        // this lane's xg gate value (gate s, unit u) — issued early
        const float xgv = s_xg[cur][s * U + uu];

        // ---- partial dots over this lane's k-slice, all 4 gates ----
        float a0 = 0.0f, a1 = 0.0f, a2 = 0.0f, a3 = 0.0f;
        const float* hs = &s_h[cur][s * S];
#pragma unroll
        for (int kk = 0; kk < S; kk += 4) {
            float4 v = *(const float4*)(hs + kk);
            a0 = fmaf(v.x, w4[0][kk + 0], a0);
            a0 = fmaf(v.y, w4[0][kk + 1], a0);
            a0 = fmaf(v.z, w4[0][kk + 2], a0);
            a0 = fmaf(v.w, w4[0][kk + 3], a0);
            a1 = fmaf(v.x, w4[1][kk + 0], a1);
            a1 = fmaf(v.y, w4[1][kk + 1], a1);
            a1 = fmaf(v.z, w4[1][kk + 2], a1);
            a1 = fmaf(v.w, w4[1][kk + 3], a1);
            a2 = fmaf(v.x, w4[2][kk + 0], a2);
            a2 = fmaf(v.y, w4[2][kk + 1], a2);
            a2 = fmaf(v.z, w4[2][kk + 2], a2);
            a2 = fmaf(v.w, w4[2][kk + 3], a2);
            a3 = fmaf(v.x, w4[3][kk + 0], a3);
            a3 = fmaf(v.y, w4[3][kk + 1], a3);
            a3 = fmaf(v.z, w4[3][kk + 2], a3);
            a3 = fmaf(v.w, w4[3][kk + 3], a3);
        }

        // ---- quad butterfly: every lane gets all-4 gate totals ----
        a0 = dpp_add<0xB1>(a0); a0 = dpp_add<0x4E>(a0);
        a1 = dpp_add<0xB1>(a1); a1 = dpp_add<0x4E>(a1);
        a2 = dpp_add<0xB1>(a2); a2 = dpp_add<0x4E>(a2);
        a3 = dpp_add<0xB1>(a3); a3 = dpp_add<0x4E>(a3);

        // lane s finalizes gate s, distributed activation
        const float asum = (s == 0) ? a0 : (s == 1) ? a1 : (s == 2) ? a2 : a3;
        const float gs = asum + xgv;
        const float ax = fabsf(gs);
        const float y  = is_t ? (-2.0f * ax) : (-gs);
        const float r  = 1.0f / (1.0f + __expf(y));
        const float v  = is_t ? copysignf(2.0f * r - 1.0f, gs) : r;

        // gather quad values (replicated compute, no divergence)
        const float fi = dpp_mov<0x00>(v);
        const float ff = dpp_mov<0x55>(v);
        const float tc = dpp_mov<0xAA>(v);
        const float fo = dpp_mov<0xFF>(v);
        c = fmaf(ff, c, fi * tc);
        h = fo * tanh_fast(c);

        const int nxt = cur ^ 1;
        if (act_th && s == 0) {
            s_h[nxt][u] = h;
            if (!LAST) xout[((size_t)b * TC + t) * U + u] = h;
        }
        if (tid < G / 4) {
            ((float4*)s_xg[nxt])[tid] = xgn;
            if (t + 2 < TC) xgn = ((const float4*)(xgrow + (size_t)(t + 2) * G))[tid];
        }
        __syncthreads();
    }

    if (act_th && s == 0) {
        c_state[b * U + u] = c;
        h_state[b * U + u] = h;
    }
    if (LAST && tid == 0) {
        float acc = bout[0];
#pragma unroll
        for (int k = 0; k < U; ++k) acc = fmaf(s_h[cur][k], Wout[k], acc);
        dout[b] = acc;
    }
}

extern "C" void kernel_launch(void* const* d_in, const int* in_sizes, int n_in,
                              void* d_out, int out_size, void* d_ws, size_t ws_size,
                              hipStream_t stream)
{
    const float* seq  = (const float*)d_in[0];
    const float* Wx0  = (const float*)d_in[1];
    const float* Wh0  = (const float*)d_in[2];
    const float* b0   = (const float*)d_in[3];
    const float* Wx1  = (const float*)d_in[4];
    const float* Wh1  = (const float*)d_in[5];
    const float* b1   = (const float*)d_in[6];
    const float* Wx2  = (const float*)d_in[7];
    const float* Wh2  = (const float*)d_in[8];
    const float* b2   = (const float*)d_in[9];
    const float* Wx3  = (const float*)d_in[10];
    const float* Wh3  = (const float*)d_in[11];
    const float* b3   = (const float*)d_in[12];
    const float* Wout = (const float*)d_in[13];
    const float* bout = (const float*)d_in[14];
    float* out = (float*)d_out;

    // ws layout (floats)
    const size_t XG_ELEMS = (size_t)BATCH * TC * 400;  // 13,107,200
    const size_t XC_ELEMS = (size_t)BATCH * TC * 100;  //  3,276,800
    float* ws  = (float*)d_ws;
    float* XGa = ws;
    float* XGb = XGa + XG_ELEMS;
    float* Xca = XGb + XG_ELEMS;
    float* Xcb = Xca + XC_ELEMS;
    float* st  = Xcb + XC_ELEMS;                        // 8 x 32768 state floats
    float* c0 = st + 0 * 32768; float* h0 = st + 1 * 32768;
    float* c1 = st + 2 * 32768; float* h1 = st + 3 * 32768;
    float* c2 = st + 4 * 32768; float* h2 = st + 5 * 32768;
    float* c3 = st + 6 * 32768; float* h3 = st + 7 * 32768;

    const dim3 gB(BATCH);

    for (int j = 0; j < NCHUNK; ++j) {
        const int first = (j == 0) ? 1 : 0;

        // L0: A then B.  seq chunk base: + j*TC*64; batch stride 1024*64.
        xg_gemm<64, 400><<<dim3(7, 512), 256, 0, stream>>>(
            seq + (size_t)j * TC * 64, TFULL * 64, Wx0, b0, XGa);
        lstm_rec<100, 28, 448, false><<<gB, 448, 0, stream>>>(
            XGa, Wh0, Xca, c0, h0, first, nullptr, nullptr, nullptr);

        // L1
        xg_gemm<100, 320><<<dim3(5, 512), 256, 0, stream>>>(
            Xca, TC * 100, Wx1, b1, XGb);
        lstm_rec<80, 20, 320, false><<<gB, 320, 0, stream>>>(
            XGb, Wh1, Xcb, c1, h1, first, nullptr, nullptr, nullptr);

        // L2
        xg_gemm<80, 200><<<dim3(4, 512), 256, 0, stream>>>(
            Xcb, TC * 80, Wx2, b2, XGa);
        lstm_rec<50, 16, 256, false><<<gB, 256, 0, stream>>>(
            XGa, Wh2, Xca, c2, h2, first, nullptr, nullptr, nullptr);

        // L3 (LAST)
        xg_gemm<50, 120><<<dim3(2, 512), 256, 0, stream>>>(
            Xca, TC * 50, Wx3, b3, XGb);
        lstm_rec<30, 8, 128, true><<<gB, 128, 0, stream>>>(
            XGb, Wh3, nullptr, c3, h3, first, Wout, bout, out);
    }
}

// Round 6
// 3058.936 us; speedup vs baseline: 1.2303x; 1.1016x over previous
//
#include <hip/hip_runtime.h>

// Round 6: two-phase LSTM stack.
// Phase A (xg_gemm): unchanged from round 5 (tiled fp32 GEMM, xg = x@Wx + b).
// Phase B (lstm_rec) v2:
//   - NO s_xg LDS: each lane prefetches its single xg gate scalar from global
//     into a register with 2-step lookahead, ISSUED AT TOP OF STEP so the
//     compiler's vmcnt(0)-before-barrier drain is free (round 5 issued it
//     right before the barrier -> ~1000 cyc/step stall + 4-way LDS conflicts).
//   - xout h-store deferred to the top of the NEXT step (ages a full step
//     before the next barrier drain).
//   - dot only over h (K=U), 4 lanes/unit, DPP quad butterfly + distributed
//     activations, double-buffered s_h, ONE barrier per step.
// Time processed in 8 chunks of 128 steps; c/h persist in ws.

#define BATCH 256
#define TFULL 1024
#define TC    128
#define NCHUNK (TFULL / TC)

__device__ __forceinline__ float tanh_fast(float x) {
    float ax = fabsf(x);
    float e = __expf(2.0f * ax);
    float r = 1.0f - 2.0f / (e + 1.0f);
    return copysignf(r, x);
}

template<int CTRL>
__device__ __forceinline__ float dpp_add(float v) {
    int t = __builtin_amdgcn_update_dpp(0, __float_as_int(v), CTRL, 0xF, 0xF, true);
    return v + __int_as_float(t);
}
template<int CTRL>
__device__ __forceinline__ float dpp_mov(float v) {
    int t = __builtin_amdgcn_update_dpp(0, __float_as_int(v), CTRL, 0xF, 0xF, true);
    return __int_as_float(t);
}

// ---------------- Phase A: xg = x @ Wx + bias ----------------
template<int K, int N>
__global__ __launch_bounds__(256, 2)
void xg_gemm(const float* __restrict__ x, int batchStride,
             const float* __restrict__ Wx,    // [K, N]
             const float* __restrict__ bias,  // [N]
             float* __restrict__ out)
{
    constexpr int K4   = (K + 3) / 4;
    constexpr int SLAB = 64 * 4 + 4;          // words per k4-slab (+4 pad)

    const int n0   = blockIdx.x * 64;
    const int row0 = blockIdx.y * 64;
    const int tid  = threadIdx.x;
    const int tx   = tid & 15;
    const int ty   = tid >> 4;

    __shared__ __align__(16) float s_A[K4 * SLAB];   // [k4][row][ksub]
    __shared__ __align__(16) float s_B[K4 * 4 * 64]; // [k][col]

    if constexpr ((K % 4) == 0) {
        for (int i = tid; i < 64 * (K / 4); i += 256) {
            const int row = i / (K / 4);
            const int k4  = i % (K / 4);
            const int gr  = row0 + row;
            const int b   = gr >> 7;
            const int t   = gr & 127;
            float4 v = *(const float4*)(x + (size_t)b * batchStride + t * K + k4 * 4);
            *(float4*)(s_A + k4 * SLAB + row * 4) = v;
        }
    } else {
        for (int i = tid; i < 64 * K; i += 256) {
            const int row = i / K;
            const int k   = i % K;
            const int gr  = row0 + row;
            const int b   = gr >> 7;
            const int t   = gr & 127;
            s_A[(k >> 2) * SLAB + row * 4 + (k & 3)] =
                x[(size_t)b * batchStride + t * K + k];
        }
        constexpr int PAD = K4 * 4 - K;
        for (int i = tid; i < 64 * PAD; i += 256) {
            const int row = i / PAD;
            const int kk  = K + i % PAD;
            s_A[(kk >> 2) * SLAB + row * 4 + (kk & 3)] = 0.0f;
        }
    }

    for (int i = tid; i < K4 * 4 * 16; i += 256) {
        const int k  = i >> 4;
        const int c4 = i & 15;
        float4 v = {0.0f, 0.0f, 0.0f, 0.0f};
        if (k < K && n0 + c4 * 4 < N)
            v = *(const float4*)(Wx + (size_t)k * N + n0 + c4 * 4);
        *(float4*)(s_B + k * 64 + c4 * 4) = v;
    }
    __syncthreads();

    float acc[4][4];
#pragma unroll
    for (int r = 0; r < 4; ++r)
#pragma unroll
        for (int c = 0; c < 4; ++c) acc[r][c] = 0.0f;

    for (int k4 = 0; k4 < K4; ++k4) {
        float4 bv[4];
#pragma unroll
        for (int j = 0; j < 4; ++j)
            bv[j] = *(const float4*)(s_B + (k4 * 4 + j) * 64 + tx * 4);
#pragma unroll
        for (int r = 0; r < 4; ++r) {
            float4 av = *(const float4*)(s_A + k4 * SLAB + (ty + 16 * r) * 4);
#pragma unroll
            for (int c = 0; c < 4; ++c) {
                acc[r][c] = fmaf(av.x, ((const float*)&bv[0])[c], acc[r][c]);
                acc[r][c] = fmaf(av.y, ((const float*)&bv[1])[c], acc[r][c]);
                acc[r][c] = fmaf(av.z, ((const float*)&bv[2])[c], acc[r][c]);
                acc[r][c] = fmaf(av.w, ((const float*)&bv[3])[c], acc[r][c]);
            }
        }
    }

    if (n0 + tx * 4 < N) {
        float4 bb = *(const float4*)(bias + n0 + tx * 4);
#pragma unroll
        for (int r = 0; r < 4; ++r) {
            float4 o;
            o.x = acc[r][0] + bb.x;
            o.y = acc[r][1] + bb.y;
            o.z = acc[r][2] + bb.z;
            o.w = acc[r][3] + bb.w;
            *(float4*)(out + (size_t)(row0 + ty + 16 * r) * N + n0 + tx * 4) = o;
        }
    }
}

// ---------------- Phase B: recurrence over one 128-step chunk ----------------
// 4 lanes per unit (quad-aligned). S: per-lane k-slice (mult of 4, 4*S >= U).
template<int U, int S, int BLOCK, bool LAST>
__global__ __launch_bounds__(BLOCK, 1)
void lstm_rec(const float* __restrict__ xg,   // [B, TC, G]
              const float* __restrict__ Wh,   // [U, G]
              float* __restrict__ xout,       // [B, TC, U] (unless LAST)
              float* __restrict__ c_state,    // [B*U]
              float* __restrict__ h_state,    // [B*U]
              int first,
              const float* __restrict__ Wout, // [U] (LAST)
              const float* __restrict__ bout, // [1] (LAST)
              float* __restrict__ dout)       // [B] (LAST)
{
    constexpr int G = 4 * U;

    const int b   = blockIdx.x;
    const int tid = threadIdx.x;
    const int u   = tid >> 2;
    const int s   = tid & 3;
    const bool act_th = (u < U);
    const int uu  = act_th ? u : 0;

    __shared__ __align__(16) float s_h[2][4 * S];

    // Each lane: partials for ALL 4 gates over its k-slice of unit uu.
    float w4[4][S];
#pragma unroll
    for (int g = 0; g < 4; ++g)
#pragma unroll
        for (int kk = 0; kk < S; ++kk) {
            const int k = s * S + kk;
            w4[g][kk] = (act_th && k < U) ? Wh[(size_t)k * G + g * U + uu] : 0.0f;
        }

    // zero both h buffers (pads must stay 0), then load carry-in state
    for (int i = tid; i < 2 * 4 * S; i += BLOCK) ((float*)s_h)[i] = 0.0f;
    __syncthreads();
    if (tid < U) s_h[0][tid] = first ? 0.0f : h_state[b * U + tid];
    float c = first ? 0.0f : c_state[b * U + uu];   // replicated across the quad
    __syncthreads();

    // per-lane xg column pointer: gate s, unit uu
    const float* xgp = xg + (size_t)b * TC * G + (s * U + uu);
    float xg0 = xgp[0];                 // t = 0
    float xg1 = xgp[G];                 // t = 1

    int cur = 0;
    float h = 0.0f, hprev = 0.0f;
    const bool is_t = (s == 2);

    for (int t = 0; t < TC; ++t, cur ^= 1) {
        // (1) issue the t+2 prefetch FIRST: ~a full dot-phase of age before
        //     the barrier's vmcnt(0) drain.
        const int tp = (t + 2 < TC) ? (t + 2) : (TC - 1);
        const float xg2 = xgp[(size_t)tp * G];

        // (2) deferred global store of last step's h (also ages before drain)
        if (!LAST) {
            if (act_th && s == 0 && t > 0)
                xout[((size_t)b * TC + (t - 1)) * U + u] = hprev;
        }

        // (3) partial dots over this lane's k-slice, all 4 gates
        float a0 = 0.0f, a1 = 0.0f, a2 = 0.0f, a3 = 0.0f;
        const float* hs = &s_h[cur][s * S];
#pragma unroll
        for (int kk = 0; kk < S; kk += 4) {
            float4 v = *(const float4*)(hs + kk);
            a0 = fmaf(v.x, w4[0][kk + 0], a0);
            a0 = fmaf(v.y, w4[0][kk + 1], a0);
            a0 = fmaf(v.z, w4[0][kk + 2], a0);
            a0 = fmaf(v.w, w4[0][kk + 3], a0);
            a1 = fmaf(v.x, w4[1][kk + 0], a1);
            a1 = fmaf(v.y, w4[1][kk + 1], a1);
            a1 = fmaf(v.z, w4[1][kk + 2], a1);
            a1 = fmaf(v.w, w4[1][kk + 3], a1);
            a2 = fmaf(v.x, w4[2][kk + 0], a2);
            a2 = fmaf(v.y, w4[2][kk + 1], a2);
            a2 = fmaf(v.z, w4[2][kk + 2], a2);
            a2 = fmaf(v.w, w4[2][kk + 3], a2);
            a3 = fmaf(v.x, w4[3][kk + 0], a3);
            a3 = fmaf(v.y, w4[3][kk + 1], a3);
            a3 = fmaf(v.z, w4[3][kk + 2], a3);
            a3 = fmaf(v.w, w4[3][kk + 3], a3);
        }

        // (4) quad butterfly: every lane gets all-4 gate totals
        a0 = dpp_add<0xB1>(a0); a0 = dpp_add<0x4E>(a0);
        a1 = dpp_add<0xB1>(a1); a1 = dpp_add<0x4E>(a1);
        a2 = dpp_add<0xB1>(a2); a2 = dpp_add<0x4E>(a2);
        a3 = dpp_add<0xB1>(a3); a3 = dpp_add<0x4E>(a3);

        // (5) lane s finalizes gate s (distributed activation)
        const float asum = (s == 0) ? a0 : (s == 1) ? a1 : (s == 2) ? a2 : a3;
        const float gs = asum + xg0;
        const float y  = is_t ? (-2.0f * fabsf(gs)) : (-gs);
        const float r  = 1.0f / (1.0f + __expf(y));
        const float v  = is_t ? copysignf(2.0f * r - 1.0f, gs) : r;

        // (6) gather quad activations, update c/h (replicated, no divergence)
        const float fi = dpp_mov<0x00>(v);
        const float ff = dpp_mov<0x55>(v);
        const float tc = dpp_mov<0xAA>(v);
        const float fo = dpp_mov<0xFF>(v);
        c = fmaf(ff, c, fi * tc);
        h = fo * tanh_fast(c);

        const int nxt = cur ^ 1;
        if (act_th && s == 0) s_h[nxt][u] = h;
        hprev = h;
        xg0 = xg1; xg1 = xg2;
        __syncthreads();
    }

    if (!LAST) {
        if (act_th && s == 0)
            xout[((size_t)b * TC + (TC - 1)) * U + u] = hprev;
    }
    if (act_th && s == 0) {
        c_state[b * U + u] = c;
        h_state[b * U + u] = h;
    }
    if (LAST && tid == 0) {
        float acc = bout[0];
#pragma unroll
        for (int k = 0; k < U; ++k) acc = fmaf(s_h[cur][k], Wout[k], acc);
        dout[b] = acc;
    }
}

extern "C" void kernel_launch(void* const* d_in, const int* in_sizes, int n_in,
                              void* d_out, int out_size, void* d_ws, size_t ws_size,
                              hipStream_t stream)
{
    const float* seq  = (const float*)d_in[0];
    const float* Wx0  = (const float*)d_in[1];
    const float* Wh0  = (const float*)d_in[2];
    const float* b0   = (const float*)d_in[3];
    const float* Wx1  = (const float*)d_in[4];
    const float* Wh1  = (const float*)d_in[5];
    const float* b1   = (const float*)d_in[6];
    const float* Wx2  = (const float*)d_in[7];
    const float* Wh2  = (const float*)d_in[8];
    const float* b2   = (const float*)d_in[9];
    const float* Wx3  = (const float*)d_in[10];
    const float* Wh3  = (const float*)d_in[11];
    const float* b3   = (const float*)d_in[12];
    const float* Wout = (const float*)d_in[13];
    const float* bout = (const float*)d_in[14];
    float* out = (float*)d_out;

    const size_t XG_ELEMS = (size_t)BATCH * TC * 400;
    const size_t XC_ELEMS = (size_t)BATCH * TC * 100;
    float* ws  = (float*)d_ws;
    float* XGa = ws;
    float* XGb = XGa + XG_ELEMS;
    float* Xca = XGb + XG_ELEMS;
    float* Xcb = Xca + XC_ELEMS;
    float* st  = Xcb + XC_ELEMS;
    float* c0 = st + 0 * 32768; float* h0 = st + 1 * 32768;
    float* c1 = st + 2 * 32768; float* h1 = st + 3 * 32768;
    float* c2 = st + 4 * 32768; float* h2 = st + 5 * 32768;
    float* c3 = st + 6 * 32768; float* h3 = st + 7 * 32768;

    const dim3 gB(BATCH);

    for (int j = 0; j < NCHUNK; ++j) {
        const int first = (j == 0) ? 1 : 0;

        xg_gemm<64, 400><<<dim3(7, 512), 256, 0, stream>>>(
            seq + (size_t)j * TC * 64, TFULL * 64, Wx0, b0, XGa);
        lstm_rec<100, 28, 448, false><<<gB, 448, 0, stream>>>(
            XGa, Wh0, Xca, c0, h0, first, nullptr, nullptr, nullptr);

        xg_gemm<100, 320><<<dim3(5, 512), 256, 0, stream>>>(
            Xca, TC * 100, Wx1, b1, XGb);
        lstm_rec<80, 20, 320, false><<<gB, 320, 0, stream>>>(
            XGb, Wh1, Xcb, c1, h1, first, nullptr, nullptr, nullptr);

        xg_gemm<80, 200><<<dim3(4, 512), 256, 0, stream>>>(
            Xcb, TC * 80, Wx2, b2, XGa);
        lstm_rec<50, 16, 256, false><<<gB, 256, 0, stream>>>(
            XGa, Wh2, Xca, c2, h2, first, nullptr, nullptr, nullptr);

        xg_gemm<50, 120><<<dim3(2, 512), 256, 0, stream>>>(
            Xca, TC * 50, Wx3, b3, XGb);
        lstm_rec<30, 8, 128, true><<<gB, 128, 0, stream>>>(
            XGb, Wh3, nullptr, c3, h3, first, Wout, bout, out);
    }
}

// Round 8
// 3017.713 us; speedup vs baseline: 1.2471x; 1.0137x over previous
//
#include <hip/hip_runtime.h>

// Round 8: R6 structure (passing, 3059 us) + SAFE occupancy pin on the rec
// kernels: amdgpu_flat_work_group_size(B,B) + amdgpu_waves_per_eu(1,2).
//   - min=1 (R7's min=2 / min=max pins are a hard codegen constraint and the
//     likely abort cause) -> always feasible.
//   - max=2 -> allocator budget 256 regs/wave so the per-lane weight arrays
//     (112/80/64/32 floats) live in arch VGPRs, killing the v_accvgpr_read
//     tax (R6: VALUBusy 2.4x issue model at VGPR_Count=72).
// Everything else identical to R6: xg GEMM phase + rec phase with 4 lanes
// per unit, DPP quad butterfly, distributed activations, top-of-step xg
// prefetch, deferred h store, 1 barrier/step, 8 time-chunks of 128.

#define BATCH 256
#define TFULL 1024
#define TC    128
#define NCHUNK (TFULL / TC)

__device__ __forceinline__ float tanh_fast(float x) {
    float ax = fabsf(x);
    float e = __expf(2.0f * ax);
    float r = 1.0f - 2.0f / (e + 1.0f);
    return copysignf(r, x);
}

template<int CTRL>
__device__ __forceinline__ float dpp_add(float v) {
    int t = __builtin_amdgcn_update_dpp(0, __float_as_int(v), CTRL, 0xF, 0xF, true);
    return v + __int_as_float(t);
}
template<int CTRL>
__device__ __forceinline__ float dpp_mov(float v) {
    int t = __builtin_amdgcn_update_dpp(0, __float_as_int(v), CTRL, 0xF, 0xF, true);
    return __int_as_float(t);
}

// ---------------- Phase A: xg = x @ Wx + bias ----------------
template<int K, int N>
__global__ __launch_bounds__(256, 2)
void xg_gemm(const float* __restrict__ x, int batchStride,
             const float* __restrict__ Wx,    // [K, N]
             const float* __restrict__ bias,  // [N]
             float* __restrict__ out)
{
    constexpr int K4   = (K + 3) / 4;
    constexpr int SLAB = 64 * 4 + 4;

    const int n0   = blockIdx.x * 64;
    const int row0 = blockIdx.y * 64;
    const int tid  = threadIdx.x;
    const int tx   = tid & 15;
    const int ty   = tid >> 4;

    __shared__ __align__(16) float s_A[K4 * SLAB];
    __shared__ __align__(16) float s_B[K4 * 4 * 64];

    if constexpr ((K % 4) == 0) {
        for (int i = tid; i < 64 * (K / 4); i += 256) {
            const int row = i / (K / 4);
            const int k4  = i % (K / 4);
            const int gr  = row0 + row;
            const int b   = gr >> 7;
            const int t   = gr & 127;
            float4 v = *(const float4*)(x + (size_t)b * batchStride + t * K + k4 * 4);
            *(float4*)(s_A + k4 * SLAB + row * 4) = v;
        }
    } else {
        for (int i = tid; i < 64 * K; i += 256) {
            const int row = i / K;
            const int k   = i % K;
            const int gr  = row0 + row;
            const int b   = gr >> 7;
            const int t   = gr & 127;
            s_A[(k >> 2) * SLAB + row * 4 + (k & 3)] =
                x[(size_t)b * batchStride + t * K + k];
        }
        constexpr int PAD = K4 * 4 - K;
        for (int i = tid; i < 64 * PAD; i += 256) {
            const int row = i / PAD;
            const int kk  = K + i % PAD;
            s_A[(kk >> 2) * SLAB + row * 4 + (kk & 3)] = 0.0f;
        }
    }

    for (int i = tid; i < K4 * 4 * 16; i += 256) {
        const int k  = i >> 4;
        const int c4 = i & 15;
        float4 v = {0.0f, 0.0f, 0.0f, 0.0f};
        if (k < K && n0 + c4 * 4 < N)
            v = *(const float4*)(Wx + (size_t)k * N + n0 + c4 * 4);
        *(float4*)(s_B + k * 64 + c4 * 4) = v;
    }
    __syncthreads();

    float acc[4][4];
#pragma unroll
    for (int r = 0; r < 4; ++r)
#pragma unroll
        for (int c = 0; c < 4; ++c) acc[r][c] = 0.0f;

    for (int k4 = 0; k4 < K4; ++k4) {
        float4 bv[4];
#pragma unroll
        for (int j = 0; j < 4; ++j)
            bv[j] = *(const float4*)(s_B + (k4 * 4 + j) * 64 + tx * 4);
#pragma unroll
        for (int r = 0; r < 4; ++r) {
            float4 av = *(const float4*)(s_A + k4 * SLAB + (ty + 16 * r) * 4);
#pragma unroll
            for (int c = 0; c < 4; ++c) {
                acc[r][c] = fmaf(av.x, ((const float*)&bv[0])[c], acc[r][c]);
                acc[r][c] = fmaf(av.y, ((const float*)&bv[1])[c], acc[r][c]);
                acc[r][c] = fmaf(av.z, ((const float*)&bv[2])[c], acc[r][c]);
                acc[r][c] = fmaf(av.w, ((const float*)&bv[3])[c], acc[r][c]);
            }
        }
    }

    if (n0 + tx * 4 < N) {
        float4 bb = *(const float4*)(bias + n0 + tx * 4);
#pragma unroll
        for (int r = 0; r < 4; ++r) {
            float4 o;
            o.x = acc[r][0] + bb.x;
            o.y = acc[r][1] + bb.y;
            o.z = acc[r][2] + bb.z;
            o.w = acc[r][3] + bb.w;
            *(float4*)(out + (size_t)(row0 + ty + 16 * r) * N + n0 + tx * 4) = o;
        }
    }
}

// ---------------- Phase B: recurrence body ----------------
// 4 lanes per unit (quad-aligned). S: per-lane k-slice (mult of 4, 4*S >= U).
template<int U, int S, int BLOCK, bool LAST>
__device__ __forceinline__ void rec_body(
    const float* __restrict__ xg,   // [B, TC, G]
    const float* __restrict__ Wh,   // [U, G]
    float* __restrict__ xout,       // [B, TC, U] (unless LAST)
    float* __restrict__ c_state,    // [B*U]
    float* __restrict__ h_state,    // [B*U]
    int first,
    const float* __restrict__ Wout, // [U] (LAST)
    const float* __restrict__ bout, // [1] (LAST)
    float* __restrict__ dout)       // [B] (LAST)
{
    constexpr int G = 4 * U;

    const int b   = blockIdx.x;
    const int tid = threadIdx.x;
    const int u   = tid >> 2;
    const int s   = tid & 3;
    const bool act_th = (u < U);
    const int uu  = act_th ? u : 0;

    __shared__ __align__(16) float s_h[2][4 * S];

    float w4[4][S];
#pragma unroll
    for (int g = 0; g < 4; ++g)
#pragma unroll
        for (int kk = 0; kk < S; ++kk) {
            const int k = s * S + kk;
            w4[g][kk] = (act_th && k < U) ? Wh[(size_t)k * G + g * U + uu] : 0.0f;
        }

    for (int i = tid; i < 2 * 4 * S; i += BLOCK) ((float*)s_h)[i] = 0.0f;
    __syncthreads();
    if (tid < U) s_h[0][tid] = first ? 0.0f : h_state[b * U + tid];
    float c = first ? 0.0f : c_state[b * U + uu];
    __syncthreads();

    const float* xgp = xg + (size_t)b * TC * G + (s * U + uu);
    float xg0 = xgp[0];
    float xg1 = xgp[G];

    int cur = 0;
    float h = 0.0f, hprev = 0.0f;
    const bool is_t = (s == 2);

    for (int t = 0; t < TC; ++t, cur ^= 1) {
        // (1) t+2 prefetch first — ages a full dot-phase before the barrier drain
        const int tp = (t + 2 < TC) ? (t + 2) : (TC - 1);
        const float xg2 = xgp[(size_t)tp * G];

        // (2) deferred global store of last step's h
        if (!LAST) {
            if (act_th && s == 0 && t > 0)
                xout[((size_t)b * TC + (t - 1)) * U + u] = hprev;
        }

        // (3) partial dots over this lane's k-slice, all 4 gates
        float a0 = 0.0f, a1 = 0.0f, a2 = 0.0f, a3 = 0.0f;
        const float* hs = &s_h[cur][s * S];
#pragma unroll
        for (int kk = 0; kk < S; kk += 4) {
            float4 v = *(const float4*)(hs + kk);
            a0 = fmaf(v.x, w4[0][kk + 0], a0);
            a0 = fmaf(v.y, w4[0][kk + 1], a0);
            a0 = fmaf(v.z, w4[0][kk + 2], a0);
            a0 = fmaf(v.w, w4[0][kk + 3], a0);
            a1 = fmaf(v.x, w4[1][kk + 0], a1);
            a1 = fmaf(v.y, w4[1][kk + 1], a1);
            a1 = fmaf(v.z, w4[1][kk + 2], a1);
            a1 = fmaf(v.w, w4[1][kk + 3], a1);
            a2 = fmaf(v.x, w4[2][kk + 0], a2);
            a2 = fmaf(v.y, w4[2][kk + 1], a2);
            a2 = fmaf(v.z, w4[2][kk + 2], a2);
            a2 = fmaf(v.w, w4[2][kk + 3], a2);
            a3 = fmaf(v.x, w4[3][kk + 0], a3);
            a3 = fmaf(v.y, w4[3][kk + 1], a3);
            a3 = fmaf(v.z, w4[3][kk + 2], a3);
            a3 = fmaf(v.w, w4[3][kk + 3], a3);
        }

        // (4) quad butterfly
        a0 = dpp_add<0xB1>(a0); a0 = dpp_add<0x4E>(a0);
        a1 = dpp_add<0xB1>(a1); a1 = dpp_add<0x4E>(a1);
        a2 = dpp_add<0xB1>(a2); a2 = dpp_add<0x4E>(a2);
        a3 = dpp_add<0xB1>(a3); a3 = dpp_add<0x4E>(a3);

        // (5) lane s finalizes gate s (distributed activation)
        const float asum = (s == 0) ? a0 : (s == 1) ? a1 : (s == 2) ? a2 : a3;
        const float gs = asum + xg0;
        const float y  = is_t ? (-2.0f * fabsf(gs)) : (-gs);
        const float r  = 1.0f / (1.0f + __expf(y));
        const float v  = is_t ? copysignf(2.0f * r - 1.0f, gs) : r;

        // (6) gather quad activations, update c/h (replicated)
        const float fi = dpp_mov<0x00>(v);
        const float ff = dpp_mov<0x55>(v);
        const float tc = dpp_mov<0xAA>(v);
        const float fo = dpp_mov<0xFF>(v);
        c = fmaf(ff, c, fi * tc);
        h = fo * tanh_fast(c);

        const int nxt = cur ^ 1;
        if (act_th && s == 0) s_h[nxt][u] = h;
        hprev = h;
        xg0 = xg1; xg1 = xg2;
        __syncthreads();
    }

    if (!LAST) {
        if (act_th && s == 0)
            xout[((size_t)b * TC + (TC - 1)) * U + u] = hprev;
    }
    if (act_th && s == 0) {
        c_state[b * U + u] = c;
        h_state[b * U + u] = h;
    }
    if (LAST && tid == 0) {
        float acc = bout[0];
#pragma unroll
        for (int k = 0; k < U; ++k) acc = fmaf(s_h[cur][k], Wout[k], acc);
        dout[b] = acc;
    }
}

#define REC_ARGS const float* __restrict__ xg, const float* __restrict__ Wh,        \
                 float* __restrict__ xout, float* __restrict__ c_state,             \
                 float* __restrict__ h_state, int first,                            \
                 const float* __restrict__ Wout, const float* __restrict__ bout,    \
                 float* __restrict__ dout
#define REC_PASS xg, Wh, xout, c_state, h_state, first, Wout, bout, dout

// SAFE pins: min=1 (never infeasible), max=2 (256-reg allocator budget).
__attribute__((amdgpu_flat_work_group_size(448, 448), amdgpu_waves_per_eu(1, 2)))
__global__ void rec_l0(REC_ARGS) { rec_body<100, 28, 448, false>(REC_PASS); }

__attribute__((amdgpu_flat_work_group_size(320, 320), amdgpu_waves_per_eu(1, 2)))
__global__ void rec_l1(REC_ARGS) { rec_body<80, 20, 320, false>(REC_PASS); }

__attribute__((amdgpu_flat_work_group_size(256, 256), amdgpu_waves_per_eu(1, 2)))
__global__ void rec_l2(REC_ARGS) { rec_body<50, 16, 256, false>(REC_PASS); }

__attribute__((amdgpu_flat_work_group_size(128, 128), amdgpu_waves_per_eu(1, 2)))
__global__ void rec_l3(REC_ARGS) { rec_body<30, 8, 128, true>(REC_PASS); }

extern "C" void kernel_launch(void* const* d_in, const int* in_sizes, int n_in,
                              void* d_out, int out_size, void* d_ws, size_t ws_size,
                              hipStream_t stream)
{
    const float* seq  = (const float*)d_in[0];
    const float* Wx0  = (const float*)d_in[1];
    const float* Wh0  = (const float*)d_in[2];
    const float* b0   = (const float*)d_in[3];
    const float* Wx1  = (const float*)d_in[4];
    const float* Wh1  = (const float*)d_in[5];
    const float* b1   = (const float*)d_in[6];
    const float* Wx2  = (const float*)d_in[7];
    const float* Wh2  = (const float*)d_in[8];
    const float* b2   = (const float*)d_in[9];
    const float* Wx3  = (const float*)d_in[10];
    const float* Wh3  = (const float*)d_in[11];
    const float* b3   = (const float*)d_in[12];
    const float* Wout = (const float*)d_in[13];
    const float* bout = (const float*)d_in[14];
    float* out = (float*)d_out;

    const size_t XG_ELEMS = (size_t)BATCH * TC * 400;
    const size_t XC_ELEMS = (size_t)BATCH * TC * 100;
    float* ws  = (float*)d_ws;
    float* XGa = ws;
    float* XGb = XGa + XG_ELEMS;
    float* Xca = XGb + XG_ELEMS;
    float* Xcb = Xca + XC_ELEMS;
    float* st  = Xcb + XC_ELEMS;
    float* c0 = st + 0 * 32768; float* h0 = st + 1 * 32768;
    float* c1 = st + 2 * 32768; float* h1 = st + 3 * 32768;
    float* c2 = st + 4 * 32768; float* h2 = st + 5 * 32768;
    float* c3 = st + 6 * 32768; float* h3 = st + 7 * 32768;

    const dim3 gB(BATCH);

    for (int j = 0; j < NCHUNK; ++j) {
        const int first = (j == 0) ? 1 : 0;

        xg_gemm<64, 400><<<dim3(7, 512), 256, 0, stream>>>(
            seq + (size_t)j * TC * 64, TFULL * 64, Wx0, b0, XGa);
        rec_l0<<<gB, 448, 0, stream>>>(
            XGa, Wh0, Xca, c0, h0, first, nullptr, nullptr, nullptr);

        xg_gemm<100, 320><<<dim3(5, 512), 256, 0, stream>>>(
            Xca, TC * 100, Wx1, b1, XGb);
        rec_l1<<<gB, 320, 0, stream>>>(
            XGb, Wh1, Xcb, c1, h1, first, nullptr, nullptr, nullptr);

        xg_gemm<80, 200><<<dim3(4, 512), 256, 0, stream>>>(
            Xcb, TC * 80, Wx2, b2, XGa);
        rec_l2<<<gB, 256, 0, stream>>>(
            XGa, Wh2, Xca, c2, h2, first, nullptr, nullptr, nullptr);

        xg_gemm<50, 120><<<dim3(2, 512), 256, 0, stream>>>(
            Xca, TC * 50, Wx3, b3, XGb);
        rec_l3<<<gB, 128, 0, stream>>>(
            XGb, Wh3, nullptr, c3, h3, first, Wout, bout, out);
    }
}

// Round 9
// 2874.307 us; speedup vs baseline: 1.3093x; 1.0499x over previous
//
#include <hip/hip_runtime.h>

// Round 9: R8 structure (passing, 3018 us) with ONE change: all divisions in
// the recurrence replaced by __builtin_amdgcn_rcpf (raw v_rcp_f32).
// R8 post-mortem: register attributes were neutral (VGPR_Count=72 unchanged,
// dur unchanged) -> no AGPR tax exists on gfx950 (VALU reads AGPRs directly).
// The ~1100 cyc/step gap over the issue model is critical-path latency, and
// the two IEEE divides per lane per step (sigmoid 1/(1+e), tanh 2/(e+1) ->
// v_div_scale/v_div_fmas/v_div_fixup, ~12 ops + ~50 cyc serial each) sit
// exactly on the serial chain: activation -> c -> tanh(c) -> h -> barrier.
// rcp error ~1e-7/step, accumulated ~1e-5 << 1.36e-3 threshold.

#define BATCH 256
#define TFULL 1024
#define TC    128
#define NCHUNK (TFULL / TC)

__device__ __forceinline__ float fast_rcp(float x) {
    return __builtin_amdgcn_rcpf(x);
}

// tanh(x) = sign(x) * (2/(1+e^{-2|x|}) - 1), via v_exp + v_rcp only.
__device__ __forceinline__ float tanh_fast(float x) {
    float e = __expf(-2.0f * fabsf(x));
    float r = fast_rcp(1.0f + e);
    return copysignf(fmaf(2.0f, r, -1.0f), x);
}

template<int CTRL>
__device__ __forceinline__ float dpp_add(float v) {
    int t = __builtin_amdgcn_update_dpp(0, __float_as_int(v), CTRL, 0xF, 0xF, true);
    return v + __int_as_float(t);
}
template<int CTRL>
__device__ __forceinline__ float dpp_mov(float v) {
    int t = __builtin_amdgcn_update_dpp(0, __float_as_int(v), CTRL, 0xF, 0xF, true);
    return __int_as_float(t);
}

// ---------------- Phase A: xg = x @ Wx + bias ----------------
template<int K, int N>
__global__ __launch_bounds__(256, 2)
void xg_gemm(const float* __restrict__ x, int batchStride,
             const float* __restrict__ Wx,    // [K, N]
             const float* __restrict__ bias,  // [N]
             float* __restrict__ out)
{
    constexpr int K4   = (K + 3) / 4;
    constexpr int SLAB = 64 * 4 + 4;

    const int n0   = blockIdx.x * 64;
    const int row0 = blockIdx.y * 64;
    const int tid  = threadIdx.x;
    const int tx   = tid & 15;
    const int ty   = tid >> 4;

    __shared__ __align__(16) float s_A[K4 * SLAB];
    __shared__ __align__(16) float s_B[K4 * 4 * 64];

    if constexpr ((K % 4) == 0) {
        for (int i = tid; i < 64 * (K / 4); i += 256) {
            const int row = i / (K / 4);
            const int k4  = i % (K / 4);
            const int gr  = row0 + row;
            const int b   = gr >> 7;
            const int t   = gr & 127;
            float4 v = *(const float4*)(x + (size_t)b * batchStride + t * K + k4 * 4);
            *(float4*)(s_A + k4 * SLAB + row * 4) = v;
        }
    } else {
        for (int i = tid; i < 64 * K; i += 256) {
            const int row = i / K;
            const int k   = i % K;
            const int gr  = row0 + row;
            const int b   = gr >> 7;
            const int t   = gr & 127;
            s_A[(k >> 2) * SLAB + row * 4 + (k & 3)] =
                x[(size_t)b * batchStride + t * K + k];
        }
        constexpr int PAD = K4 * 4 - K;
        for (int i = tid; i < 64 * PAD; i += 256) {
            const int row = i / PAD;
            const int kk  = K + i % PAD;
            s_A[(kk >> 2) * SLAB + row * 4 + (kk & 3)] = 0.0f;
        }
    }

    for (int i = tid; i < K4 * 4 * 16; i += 256) {
        const int k  = i >> 4;
        const int c4 = i & 15;
        float4 v = {0.0f, 0.0f, 0.0f, 0.0f};
        if (k < K && n0 + c4 * 4 < N)
            v = *(const float4*)(Wx + (size_t)k * N + n0 + c4 * 4);
        *(float4*)(s_B + k * 64 + c4 * 4) = v;
    }
    __syncthreads();

    float acc[4][4];
#pragma unroll
    for (int r = 0; r < 4; ++r)
#pragma unroll
        for (int c = 0; c < 4; ++c) acc[r][c] = 0.0f;

    for (int k4 = 0; k4 < K4; ++k4) {
        float4 bv[4];
#pragma unroll
        for (int j = 0; j < 4; ++j)
            bv[j] = *(const float4*)(s_B + (k4 * 4 + j) * 64 + tx * 4);
#pragma unroll
        for (int r = 0; r < 4; ++r) {
            float4 av = *(const float4*)(s_A + k4 * SLAB + (ty + 16 * r) * 4);
#pragma unroll
            for (int c = 0; c < 4; ++c) {
                acc[r][c] = fmaf(av.x, ((const float*)&bv[0])[c], acc[r][c]);
                acc[r][c] = fmaf(av.y, ((const float*)&bv[1])[c], acc[r][c]);
                acc[r][c] = fmaf(av.z, ((const float*)&bv[2])[c], acc[r][c]);
                acc[r][c] = fmaf(av.w, ((const float*)&bv[3])[c], acc[r][c]);
            }
        }
    }

    if (n0 + tx * 4 < N) {
        float4 bb = *(const float4*)(bias + n0 + tx * 4);
#pragma unroll
        for (int r = 0; r < 4; ++r) {
            float4 o;
            o.x = acc[r][0] + bb.x;
            o.y = acc[r][1] + bb.y;
            o.z = acc[r][2] + bb.z;
            o.w = acc[r][3] + bb.w;
            *(float4*)(out + (size_t)(row0 + ty + 16 * r) * N + n0 + tx * 4) = o;
        }
    }
}

// ---------------- Phase B: recurrence body ----------------
// 4 lanes per unit (quad-aligned). S: per-lane k-slice (mult of 4, 4*S >= U).
template<int U, int S, int BLOCK, bool LAST>
__device__ __forceinline__ void rec_body(
    const float* __restrict__ xg,   // [B, TC, G]
    const float* __restrict__ Wh,   // [U, G]
    float* __restrict__ xout,       // [B, TC, U] (unless LAST)
    float* __restrict__ c_state,    // [B*U]
    float* __restrict__ h_state,    // [B*U]
    int first,
    const float* __restrict__ Wout, // [U] (LAST)
    const float* __restrict__ bout, // [1] (LAST)
    float* __restrict__ dout)       // [B] (LAST)
{
    constexpr int G = 4 * U;

    const int b   = blockIdx.x;
    const int tid = threadIdx.x;
    const int u   = tid >> 2;
    const int s   = tid & 3;
    const bool act_th = (u < U);
    const int uu  = act_th ? u : 0;

    __shared__ __align__(16) float s_h[2][4 * S];

    float w4[4][S];
#pragma unroll
    for (int g = 0; g < 4; ++g)
#pragma unroll
        for (int kk = 0; kk < S; ++kk) {
            const int k = s * S + kk;
            w4[g][kk] = (act_th && k < U) ? Wh[(size_t)k * G + g * U + uu] : 0.0f;
        }

    for (int i = tid; i < 2 * 4 * S; i += BLOCK) ((float*)s_h)[i] = 0.0f;
    __syncthreads();
    if (tid < U) s_h[0][tid] = first ? 0.0f : h_state[b * U + tid];
    float c = first ? 0.0f : c_state[b * U + uu];
    __syncthreads();

    const float* xgp = xg + (size_t)b * TC * G + (s * U + uu);
    float xg0 = xgp[0];
    float xg1 = xgp[G];

    int cur = 0;
    float h = 0.0f, hprev = 0.0f;
    const bool is_t = (s == 2);

    for (int t = 0; t < TC; ++t, cur ^= 1) {
        // (1) t+2 prefetch first — ages a full dot-phase before the barrier drain
        const int tp = (t + 2 < TC) ? (t + 2) : (TC - 1);
        const float xg2 = xgp[(size_t)tp * G];

        // (2) deferred global store of last step's h
        if (!LAST) {
            if (act_th && s == 0 && t > 0)
                xout[((size_t)b * TC + (t - 1)) * U + u] = hprev;
        }

        // (3) partial dots over this lane's k-slice, all 4 gates
        float a0 = 0.0f, a1 = 0.0f, a2 = 0.0f, a3 = 0.0f;
        const float* hs = &s_h[cur][s * S];
#pragma unroll
        for (int kk = 0; kk < S; kk += 4) {
            float4 v = *(const float4*)(hs + kk);
            a0 = fmaf(v.x, w4[0][kk + 0], a0);
            a0 = fmaf(v.y, w4[0][kk + 1], a0);
            a0 = fmaf(v.z, w4[0][kk + 2], a0);
            a0 = fmaf(v.w, w4[0][kk + 3], a0);
            a1 = fmaf(v.x, w4[1][kk + 0], a1);
            a1 = fmaf(v.y, w4[1][kk + 1], a1);
            a1 = fmaf(v.z, w4[1][kk + 2], a1);
            a1 = fmaf(v.w, w4[1][kk + 3], a1);
            a2 = fmaf(v.x, w4[2][kk + 0], a2);
            a2 = fmaf(v.y, w4[2][kk + 1], a2);
            a2 = fmaf(v.z, w4[2][kk + 2], a2);
            a2 = fmaf(v.w, w4[2][kk + 3], a2);
            a3 = fmaf(v.x, w4[3][kk + 0], a3);
            a3 = fmaf(v.y, w4[3][kk + 1], a3);
            a3 = fmaf(v.z, w4[3][kk + 2], a3);
            a3 = fmaf(v.w, w4[3][kk + 3], a3);
        }

        // (4) quad butterfly
        a0 = dpp_add<0xB1>(a0); a0 = dpp_add<0x4E>(a0);
        a1 = dpp_add<0xB1>(a1); a1 = dpp_add<0x4E>(a1);
        a2 = dpp_add<0xB1>(a2); a2 = dpp_add<0x4E>(a2);
        a3 = dpp_add<0xB1>(a3); a3 = dpp_add<0x4E>(a3);

        // (5) lane s finalizes gate s (distributed activation).
        //     shared form: r = rcp(1 + exp(y)); sigmoid: y=-x -> r;
        //     tanh: y=-2|x| -> 2r-1, restore sign.
        const float asum = (s == 0) ? a0 : (s == 1) ? a1 : (s == 2) ? a2 : a3;
        const float gs = asum + xg0;
        const float y  = is_t ? (-2.0f * fabsf(gs)) : (-gs);
        const float r  = fast_rcp(1.0f + __expf(y));
        const float v  = is_t ? copysignf(fmaf(2.0f, r, -1.0f), gs) : r;

        // (6) gather quad activations, update c/h (replicated)
        const float fi = dpp_mov<0x00>(v);
        const float ff = dpp_mov<0x55>(v);
        const float tc = dpp_mov<0xAA>(v);
        const float fo = dpp_mov<0xFF>(v);
        c = fmaf(ff, c, fi * tc);
        h = fo * tanh_fast(c);

        const int nxt = cur ^ 1;
        if (act_th && s == 0) s_h[nxt][u] = h;
        hprev = h;
        xg0 = xg1; xg1 = xg2;
        __syncthreads();
    }

    if (!LAST) {
        if (act_th && s == 0)
            xout[((size_t)b * TC + (TC - 1)) * U + u] = hprev;
    }
    if (act_th && s == 0) {
        c_state[b * U + u] = c;
        h_state[b * U + u] = h;
    }
    if (LAST && tid == 0) {
        float acc = bout[0];
#pragma unroll
        for (int k = 0; k < U; ++k) acc = fmaf(s_h[cur][k], Wout[k], acc);
        dout[b] = acc;
    }
}

#define REC_ARGS const float* __restrict__ xg, const float* __restrict__ Wh,        \
                 float* __restrict__ xout, float* __restrict__ c_state,             \
                 float* __restrict__ h_state, int first,                            \
                 const float* __restrict__ Wout, const float* __restrict__ bout,    \
                 float* __restrict__ dout
#define REC_PASS xg, Wh, xout, c_state, h_state, first, Wout, bout, dout

__attribute__((amdgpu_flat_work_group_size(448, 448), amdgpu_waves_per_eu(1, 2)))
__global__ void rec_l0(REC_ARGS) { rec_body<100, 28, 448, false>(REC_PASS); }

__attribute__((amdgpu_flat_work_group_size(320, 320), amdgpu_waves_per_eu(1, 2)))
__global__ void rec_l1(REC_ARGS) { rec_body<80, 20, 320, false>(REC_PASS); }

__attribute__((amdgpu_flat_work_group_size(256, 256), amdgpu_waves_per_eu(1, 2)))
__global__ void rec_l2(REC_ARGS) { rec_body<50, 16, 256, false>(REC_PASS); }

__attribute__((amdgpu_flat_work_group_size(128, 128), amdgpu_waves_per_eu(1, 2)))
__global__ void rec_l3(REC_ARGS) { rec_body<30, 8, 128, true>(REC_PASS); }

extern "C" void kernel_launch(void* const* d_in, const int* in_sizes, int n_in,
                              void* d_out, int out_size, void* d_ws, size_t ws_size,
                              hipStream_t stream)
{
    const float* seq  = (const float*)d_in[0];
    const float* Wx0  = (const float*)d_in[1];
    const float* Wh0  = (const float*)d_in[2];
    const float* b0   = (const float*)d_in[3];
    const float* Wx1  = (const float*)d_in[4];
    const float* Wh1  = (const float*)d_in[5];
    const float* b1   = (const float*)d_in[6];
    const float* Wx2  = (const float*)d_in[7];
    const float* Wh2  = (const float*)d_in[8];
    const float* b2   = (const float*)d_in[9];
    const float* Wx3  = (const float*)d_in[10];
    const float* Wh3  = (const float*)d_in[11];
    const float* b3   = (const float*)d_in[12];
    const float* Wout = (const float*)d_in[13];
    const float* bout = (const float*)d_in[14];
    float* out = (float*)d_out;

    const size_t XG_ELEMS = (size_t)BATCH * TC * 400;
    const size_t XC_ELEMS = (size_t)BATCH * TC * 100;
    float* ws  = (float*)d_ws;
    float* XGa = ws;
    float* XGb = XGa + XG_ELEMS;
    float* Xca = XGb + XG_ELEMS;
    float* Xcb = Xca + XC_ELEMS;
    float* st  = Xcb + XC_ELEMS;
    float* c0 = st + 0 * 32768; float* h0 = st + 1 * 32768;
    float* c1 = st + 2 * 32768; float* h1 = st + 3 * 32768;
    float* c2 = st + 4 * 32768; float* h2 = st + 5 * 32768;
    float* c3 = st + 6 * 32768; float* h3 = st + 7 * 32768;

    const dim3 gB(BATCH);

    for (int j = 0; j < NCHUNK; ++j) {
        const int first = (j == 0) ? 1 : 0;

        xg_gemm<64, 400><<<dim3(7, 512), 256, 0, stream>>>(
            seq + (size_t)j * TC * 64, TFULL * 64, Wx0, b0, XGa);
        rec_l0<<<gB, 448, 0, stream>>>(
            XGa, Wh0, Xca, c0, h0, first, nullptr, nullptr, nullptr);

        xg_gemm<100, 320><<<dim3(5, 512), 256, 0, stream>>>(
            Xca, TC * 100, Wx1, b1, XGb);
        rec_l1<<<gB, 320, 0, stream>>>(
            XGb, Wh1, Xcb, c1, h1, first, nullptr, nullptr, nullptr);

        xg_gemm<80, 200><<<dim3(4, 512), 256, 0, stream>>>(
            Xcb, TC * 80, Wx2, b2, XGa);
        rec_l2<<<gB, 256, 0, stream>>>(
            XGa, Wh2, Xca, c2, h2, first, nullptr, nullptr, nullptr);

        xg_gemm<50, 120><<<dim3(2, 512), 256, 0, stream>>>(
            Xca, TC * 50, Wx3, b3, XGb);
        rec_l3<<<gB, 128, 0, stream>>>(
            XGb, Wh3, nullptr, c3, h3, first, Wout, bout, out);
    }
}

// Round 10
// 2869.674 us; speedup vs baseline: 1.3114x; 1.0016x over previous
//
#include <hip/hip_runtime.h>

// Round 10: R9 structure (passing, 2874 us) with ONE change: the per-step
// __syncthreads() in the recurrence loop is replaced by an LDS-only barrier
//   asm("s_waitcnt lgkmcnt(0); s_barrier")
// __syncthreads lowers to s_waitcnt vmcnt(0) lgkmcnt(0) + s_barrier: every
// step it drained the in-flight xg prefetch (~900 cyc HBM latency, only
// ~400 cyc old) AND the xout h-store completion. The loop's barrier only
// orders LDS (h handoff); xg is read-only, xout is per-lane disjoint
// write-only -> no global ordering needed. Loads are then waited at USE
// (2 steps of age ~2000 cyc = free); stores never waited.

#define BATCH 256
#define TFULL 1024
#define TC    128
#define NCHUNK (TFULL / TC)

__device__ __forceinline__ float fast_rcp(float x) {
    return __builtin_amdgcn_rcpf(x);
}

// tanh(x) = sign(x) * (2/(1+e^{-2|x|}) - 1), via v_exp + v_rcp only.
__device__ __forceinline__ float tanh_fast(float x) {
    float e = __expf(-2.0f * fabsf(x));
    float r = fast_rcp(1.0f + e);
    return copysignf(fmaf(2.0f, r, -1.0f), x);
}

// LDS-only barrier: does NOT drain vmcnt (global loads/stores stay in
// flight across it). Safe iff no cross-thread global communication relies
// on this barrier — true for the rec loop.
__device__ __forceinline__ void lds_barrier() {
    asm volatile("s_waitcnt lgkmcnt(0)\n\ts_barrier" ::: "memory");
}

template<int CTRL>
__device__ __forceinline__ float dpp_add(float v) {
    int t = __builtin_amdgcn_update_dpp(0, __float_as_int(v), CTRL, 0xF, 0xF, true);
    return v + __int_as_float(t);
}
template<int CTRL>
__device__ __forceinline__ float dpp_mov(float v) {
    int t = __builtin_amdgcn_update_dpp(0, __float_as_int(v), CTRL, 0xF, 0xF, true);
    return __int_as_float(t);
}

// ---------------- Phase A: xg = x @ Wx + bias ----------------
template<int K, int N>
__global__ __launch_bounds__(256, 2)
void xg_gemm(const float* __restrict__ x, int batchStride,
             const float* __restrict__ Wx,    // [K, N]
             const float* __restrict__ bias,  // [N]
             float* __restrict__ out)
{
    constexpr int K4   = (K + 3) / 4;
    constexpr int SLAB = 64 * 4 + 4;

    const int n0   = blockIdx.x * 64;
    const int row0 = blockIdx.y * 64;
    const int tid  = threadIdx.x;
    const int tx   = tid & 15;
    const int ty   = tid >> 4;

    __shared__ __align__(16) float s_A[K4 * SLAB];
    __shared__ __align__(16) float s_B[K4 * 4 * 64];

    if constexpr ((K % 4) == 0) {
        for (int i = tid; i < 64 * (K / 4); i += 256) {
            const int row = i / (K / 4);
            const int k4  = i % (K / 4);
            const int gr  = row0 + row;
            const int b   = gr >> 7;
            const int t   = gr & 127;
            float4 v = *(const float4*)(x + (size_t)b * batchStride + t * K + k4 * 4);
            *(float4*)(s_A + k4 * SLAB + row * 4) = v;
        }
    } else {
        for (int i = tid; i < 64 * K; i += 256) {
            const int row = i / K;
            const int k   = i % K;
            const int gr  = row0 + row;
            const int b   = gr >> 7;
            const int t   = gr & 127;
            s_A[(k >> 2) * SLAB + row * 4 + (k & 3)] =
                x[(size_t)b * batchStride + t * K + k];
        }
        constexpr int PAD = K4 * 4 - K;
        for (int i = tid; i < 64 * PAD; i += 256) {
            const int row = i / PAD;
            const int kk  = K + i % PAD;
            s_A[(kk >> 2) * SLAB + row * 4 + (kk & 3)] = 0.0f;
        }
    }

    for (int i = tid; i < K4 * 4 * 16; i += 256) {
        const int k  = i >> 4;
        const int c4 = i & 15;
        float4 v = {0.0f, 0.0f, 0.0f, 0.0f};
        if (k < K && n0 + c4 * 4 < N)
            v = *(const float4*)(Wx + (size_t)k * N + n0 + c4 * 4);
        *(float4*)(s_B + k * 64 + c4 * 4) = v;
    }
    __syncthreads();

    float acc[4][4];
#pragma unroll
    for (int r = 0; r < 4; ++r)
#pragma unroll
        for (int c = 0; c < 4; ++c) acc[r][c] = 0.0f;

    for (int k4 = 0; k4 < K4; ++k4) {
        float4 bv[4];
#pragma unroll
        for (int j = 0; j < 4; ++j)
            bv[j] = *(const float4*)(s_B + (k4 * 4 + j) * 64 + tx * 4);
#pragma unroll
        for (int r = 0; r < 4; ++r) {
            float4 av = *(const float4*)(s_A + k4 * SLAB + (ty + 16 * r) * 4);
#pragma unroll
            for (int c = 0; c < 4; ++c) {
                acc[r][c] = fmaf(av.x, ((const float*)&bv[0])[c], acc[r][c]);
                acc[r][c] = fmaf(av.y, ((const float*)&bv[1])[c], acc[r][c]);
                acc[r][c] = fmaf(av.z, ((const float*)&bv[2])[c], acc[r][c]);
                acc[r][c] = fmaf(av.w, ((const float*)&bv[3])[c], acc[r][c]);
            }
        }
    }

    if (n0 + tx * 4 < N) {
        float4 bb = *(const float4*)(bias + n0 + tx * 4);
#pragma unroll
        for (int r = 0; r < 4; ++r) {
            float4 o;
            o.x = acc[r][0] + bb.x;
            o.y = acc[r][1] + bb.y;
            o.z = acc[r][2] + bb.z;
            o.w = acc[r][3] + bb.w;
            *(float4*)(out + (size_t)(row0 + ty + 16 * r) * N + n0 + tx * 4) = o;
        }
    }
}

// ---------------- Phase B: recurrence body ----------------
// 4 lanes per unit (quad-aligned). S: per-lane k-slice (mult of 4, 4*S >= U).
template<int U, int S, int BLOCK, bool LAST>
__device__ __forceinline__ void rec_body(
    const float* __restrict__ xg,   // [B, TC, G]
    const float* __restrict__ Wh,   // [U, G]
    float* __restrict__ xout,       // [B, TC, U] (unless LAST)
    float* __restrict__ c_state,    // [B*U]
    float* __restrict__ h_state,    // [B*U]
    int first,
    const float* __restrict__ Wout, // [U] (LAST)
    const float* __restrict__ bout, // [1] (LAST)
    float* __restrict__ dout)       // [B] (LAST)
{
    constexpr int G = 4 * U;

    const int b   = blockIdx.x;
    const int tid = threadIdx.x;
    const int u   = tid >> 2;
    const int s   = tid & 3;
    const bool act_th = (u < U);
    const int uu  = act_th ? u : 0;

    __shared__ __align__(16) float s_h[2][4 * S];

    float w4[4][S];
#pragma unroll
    for (int g = 0; g < 4; ++g)
#pragma unroll
        for (int kk = 0; kk < S; ++kk) {
            const int k = s * S + kk;
            w4[g][kk] = (act_th && k < U) ? Wh[(size_t)k * G + g * U + uu] : 0.0f;
        }

    for (int i = tid; i < 2 * 4 * S; i += BLOCK) ((float*)s_h)[i] = 0.0f;
    __syncthreads();
    if (tid < U) s_h[0][tid] = first ? 0.0f : h_state[b * U + tid];
    float c = first ? 0.0f : c_state[b * U + uu];
    __syncthreads();

    const float* xgp = xg + (size_t)b * TC * G + (s * U + uu);
    float xg0 = xgp[0];
    float xg1 = xgp[G];

    int cur = 0;
    float h = 0.0f, hprev = 0.0f;
    const bool is_t = (s == 2);

    for (int t = 0; t < TC; ++t, cur ^= 1) {
        // (1) t+2 prefetch: waited at USE two steps from now (~2 steps of age)
        const int tp = (t + 2 < TC) ? (t + 2) : (TC - 1);
        const float xg2 = xgp[(size_t)tp * G];

        // (2) deferred global store of last step's h (never waited at barrier)
        if (!LAST) {
            if (act_th && s == 0 && t > 0)
                xout[((size_t)b * TC + (t - 1)) * U + u] = hprev;
        }

        // (3) partial dots over this lane's k-slice, all 4 gates
        float a0 = 0.0f, a1 = 0.0f, a2 = 0.0f, a3 = 0.0f;
        const float* hs = &s_h[cur][s * S];
#pragma unroll
        for (int kk = 0; kk < S; kk += 4) {
            float4 v = *(const float4*)(hs + kk);
            a0 = fmaf(v.x, w4[0][kk + 0], a0);
            a0 = fmaf(v.y, w4[0][kk + 1], a0);
            a0 = fmaf(v.z, w4[0][kk + 2], a0);
            a0 = fmaf(v.w, w4[0][kk + 3], a0);
            a1 = fmaf(v.x, w4[1][kk + 0], a1);
            a1 = fmaf(v.y, w4[1][kk + 1], a1);
            a1 = fmaf(v.z, w4[1][kk + 2], a1);
            a1 = fmaf(v.w, w4[1][kk + 3], a1);
            a2 = fmaf(v.x, w4[2][kk + 0], a2);
            a2 = fmaf(v.y, w4[2][kk + 1], a2);
            a2 = fmaf(v.z, w4[2][kk + 2], a2);
            a2 = fmaf(v.w, w4[2][kk + 3], a2);
            a3 = fmaf(v.x, w4[3][kk + 0], a3);
            a3 = fmaf(v.y, w4[3][kk + 1], a3);
            a3 = fmaf(v.z, w4[3][kk + 2], a3);
            a3 = fmaf(v.w, w4[3][kk + 3], a3);
        }

        // (4) quad butterfly
        a0 = dpp_add<0xB1>(a0); a0 = dpp_add<0x4E>(a0);
        a1 = dpp_add<0xB1>(a1); a1 = dpp_add<0x4E>(a1);
        a2 = dpp_add<0xB1>(a2); a2 = dpp_add<0x4E>(a2);
        a3 = dpp_add<0xB1>(a3); a3 = dpp_add<0x4E>(a3);

        // (5) lane s finalizes gate s (distributed activation)
        const float asum = (s == 0) ? a0 : (s == 1) ? a1 : (s == 2) ? a2 : a3;
        const float gs = asum + xg0;
        const float y  = is_t ? (-2.0f * fabsf(gs)) : (-gs);
        const float r  = fast_rcp(1.0f + __expf(y));
        const float v  = is_t ? copysignf(fmaf(2.0f, r, -1.0f), gs) : r;

        // (6) gather quad activations, update c/h (replicated)
        const float fi = dpp_mov<0x00>(v);
        const float ff = dpp_mov<0x55>(v);
        const float tc = dpp_mov<0xAA>(v);
        const float fo = dpp_mov<0xFF>(v);
        c = fmaf(ff, c, fi * tc);
        h = fo * tanh_fast(c);

        const int nxt = cur ^ 1;
        if (act_th && s == 0) s_h[nxt][u] = h;
        hprev = h;
        xg0 = xg1; xg1 = xg2;
        lds_barrier();   // LDS-only: global ops stay in flight
    }

    if (!LAST) {
        if (act_th && s == 0)
            xout[((size_t)b * TC + (TC - 1)) * U + u] = hprev;
    }
    if (act_th && s == 0) {
        c_state[b * U + u] = c;
        h_state[b * U + u] = h;
    }
    if (LAST && tid == 0) {
        float acc = bout[0];
#pragma unroll
        for (int k = 0; k < U; ++k) acc = fmaf(s_h[cur][k], Wout[k], acc);
        dout[b] = acc;
    }
}

#define REC_ARGS const float* __restrict__ xg, const float* __restrict__ Wh,        \
                 float* __restrict__ xout, float* __restrict__ c_state,             \
                 float* __restrict__ h_state, int first,                            \
                 const float* __restrict__ Wout, const float* __restrict__ bout,    \
                 float* __restrict__ dout
#define REC_PASS xg, Wh, xout, c_state, h_state, first, Wout, bout, dout

__attribute__((amdgpu_flat_work_group_size(448, 448), amdgpu_waves_per_eu(1, 2)))
__global__ void rec_l0(REC_ARGS) { rec_body<100, 28, 448, false>(REC_PASS); }

__attribute__((amdgpu_flat_work_group_size(320, 320), amdgpu_waves_per_eu(1, 2)))
__global__ void rec_l1(REC_ARGS) { rec_body<80, 20, 320, false>(REC_PASS); }

__attribute__((amdgpu_flat_work_group_size(256, 256), amdgpu_waves_per_eu(1, 2)))
__global__ void rec_l2(REC_ARGS) { rec_body<50, 16, 256, false>(REC_PASS); }

__attribute__((amdgpu_flat_work_group_size(128, 128), amdgpu_waves_per_eu(1, 2)))
__global__ void rec_l3(REC_ARGS) { rec_body<30, 8, 128, true>(REC_PASS); }

extern "C" void kernel_launch(void* const* d_in, const int* in_sizes, int n_in,
                              void* d_out, int out_size, void* d_ws, size_t ws_size,
                              hipStream_t stream)
{
    const float* seq  = (const float*)d_in[0];
    const float* Wx0  = (const float*)d_in[1];
    const float* Wh0  = (const float*)d_in[2];
    const float* b0   = (const float*)d_in[3];
    const float* Wx1  = (const float*)d_in[4];
    const float* Wh1  = (const float*)d_in[5];
    const float* b1   = (const float*)d_in[6];
    const float* Wx2  = (const float*)d_in[7];
    const float* Wh2  = (const float*)d_in[8];
    const float* b2   = (const float*)d_in[9];
    const float* Wx3  = (const float*)d_in[10];
    const float* Wh3  = (const float*)d_in[11];
    const float* b3   = (const float*)d_in[12];
    const float* Wout = (const float*)d_in[13];
    const float* bout = (const float*)d_in[14];
    float* out = (float*)d_out;

    const size_t XG_ELEMS = (size_t)BATCH * TC * 400;
    const size_t XC_ELEMS = (size_t)BATCH * TC * 100;
    float* ws  = (float*)d_ws;
    float* XGa = ws;
    float* XGb = XGa + XG_ELEMS;
    float* Xca = XGb + XG_ELEMS;
    float* Xcb = Xca + XC_ELEMS;
    float* st  = Xcb + XC_ELEMS;
    float* c0 = st + 0 * 32768; float* h0 = st + 1 * 32768;
    float* c1 = st + 2 * 32768; float* h1 = st + 3 * 32768;
    float* c2 = st + 4 * 32768; float* h2 = st + 5 * 32768;
    float* c3 = st + 6 * 32768; float* h3 = st + 7 * 32768;

    const dim3 gB(BATCH);

    for (int j = 0; j < NCHUNK; ++j) {
        const int first = (j == 0) ? 1 : 0;

        xg_gemm<64, 400><<<dim3(7, 512), 256, 0, stream>>>(
            seq + (size_t)j * TC * 64, TFULL * 64, Wx0, b0, XGa);
        rec_l0<<<gB, 448, 0, stream>>>(
            XGa, Wh0, Xca, c0, h0, first, nullptr, nullptr, nullptr);

        xg_gemm<100, 320><<<dim3(5, 512), 256, 0, stream>>>(
            Xca, TC * 100, Wx1, b1, XGb);
        rec_l1<<<gB, 320, 0, stream>>>(
            XGb, Wh1, Xcb, c1, h1, first, nullptr, nullptr, nullptr);

        xg_gemm<80, 200><<<dim3(4, 512), 256, 0, stream>>>(
            Xcb, TC * 80, Wx2, b2, XGa);
        rec_l2<<<gB, 256, 0, stream>>>(
            XGa, Wh2, Xca, c2, h2, first, nullptr, nullptr, nullptr);

        xg_gemm<50, 120><<<dim3(2, 512), 256, 0, stream>>>(
            Xca, TC * 50, Wx3, b3, XGb);
        rec_l3<<<gB, 128, 0, stream>>>(
            XGb, Wh3, nullptr, c3, h3, first, Wout, bout, out);
    }
}